// Round 1
// 366.792 us; speedup vs baseline: 1.0141x; 1.0141x over previous
//
#include <hip/hip_runtime.h>
#include <hip/hip_bf16.h>

// out[token][o] = scale * sum_k x[token][k]*W[o][k] - scale*zp*sum_k x[token][k] + bias[o]
// M=128, K=4096, N=16384. W int32 = 256 MiB -> memory-bound (~44us floor @6.3TB/s).
// v5: same geometry as v4 (token-split waves, W staged once per block via LDS, bf16 cvt
// at staging, no K-split), but the phase loop is restructured per the T3/T4 recipe:
//   - ONE raw s_barrier per phase (the v4 barrier between compute and stash was
//     redundant: stash targets the opposite buffer; prior readers retired pre-barrier)
//   - NO __syncthreads() in the loop -> compiler never emits s_waitcnt vmcnt(0),
//     so the depth-2 W prefetch actually stays in flight across barriers
//     (counted vmcnt(6) at the Bc use point is what the compiler emits instead)
//   - explicit "s_waitcnt lgkmcnt(0)" + sched_barrier(0) fences around the barrier
//     order ds_write -> barrier -> next-phase ds_read (rule #18 discipline)

#define IN_F 4096
#define OUT_F 16384
#define NTOK 128

typedef __attribute__((ext_vector_type(8))) short bf16x8;
typedef __attribute__((ext_vector_type(4))) float f32x4;

__device__ __forceinline__ unsigned short f32_to_bf16_rne(float f) {
  unsigned u = __float_as_uint(f);
  u += 0x7fffu + ((u >> 16) & 1u);
  return (unsigned short)(u >> 16);
}

// Pack x [128][4096] f32 -> bf16 fragment-major image in ws, plus per-token sums.
// chunk(s, t, lane) at uint4 index s*512 + t*64 + lane holds
//   x[token = t*16 + (lane&15)][k = s*32 + (lane>>4)*8 + j], j=0..7.
__global__ __launch_bounds__(512) void prep_x(const float* __restrict__ x,
                                              uint4* __restrict__ xf,
                                              float* __restrict__ xsum) {
  const int token = blockIdx.x;   // 0..127
  const int i = (int)threadIdx.x; // 0..511, handles k = i*8 .. i*8+7
  const int k0 = i << 3;
  const float4 v0 = *(const float4*)(x + token * IN_F + k0);
  const float4 v1 = *(const float4*)(x + token * IN_F + k0 + 4);
  float v[8] = {v0.x, v0.y, v0.z, v0.w, v1.x, v1.y, v1.z, v1.w};
  unsigned short h[8];
  float s = 0.f;
#pragma unroll
  for (int j = 0; j < 8; ++j) {
    s += v[j];
    h[j] = f32_to_bf16_rne(v[j]);
  }
  uint4 o;
  o.x = (unsigned)h[0] | ((unsigned)h[1] << 16);
  o.y = (unsigned)h[2] | ((unsigned)h[3] << 16);
  o.z = (unsigned)h[4] | ((unsigned)h[5] << 16);
  o.w = (unsigned)h[6] | ((unsigned)h[7] << 16);
  const int slab = i >> 2;
  const int q = i & 3;
  const int lane = (q << 4) | (token & 15);
  xf[slab * 512 + (token >> 4) * 64 + lane] = o;

#pragma unroll
  for (int off = 32; off > 0; off >>= 1) s += __shfl_down(s, off, 64);
  __shared__ float wsum[8];
  if ((i & 63) == 0) wsum[i >> 6] = s;
  __syncthreads();
  if (i == 0) {
    float t = 0.f;
#pragma unroll
    for (int a = 0; a < 8; ++a) t += wsum[a];
    xsum[token] = t;
  }
}

// int in [-127,127] -> f32 exact with zero low-16 mantissa -> bf16 truncation is EXACT.
__device__ __forceinline__ void stash4(short* lds_s, int off_s, int4 v) {
  uint2 o;
  o.x = (__float_as_uint((float)v.x) >> 16) | (__float_as_uint((float)v.y) & 0xffff0000u);
  o.y = (__float_as_uint((float)v.z) >> 16) | (__float_as_uint((float)v.w) & 0xffff0000u);
  *(uint2*)(lds_s + off_s) = o;  // off_s in shorts; kk multiple of 4 -> 8B aligned
}

// LDS phase buffer layout (bf16): [s_local 0..3][row 0..31][kk 0..31]
// row stride 40 shorts (80 B, padded from 64 -> conflict-free frag reads),
// s_local stride 1280 shorts (2560 B). Phase = 5120 shorts = 10240 B. Double-buffered.
#define SROW 40
#define SSL 1280
#define SBUF 5120

// One-barrier phase boundary: my ds ops retired, then raw barrier; sched_barrier(0)
// fences keep ds_write above / next-phase ds_read below (compiler may otherwise move
// LDS ops across the raw-barrier intrinsic). Global loads are NOT fenced-drained:
// that's the whole point -- prefetch stays in flight.
__device__ __forceinline__ void phase_barrier() {
  __builtin_amdgcn_sched_barrier(0);
  asm volatile("s_waitcnt lgkmcnt(0)" ::: "memory");
  __builtin_amdgcn_s_barrier();
  __builtin_amdgcn_sched_barrier(0);
}

// Grid 512 blocks x 512 threads (8 waves). Block: 32 output rows x full K.
// Wave w owns token-tile w (16 tokens). Phase = 4 k-steps (128 k = 512 B/row of W).
// Per phase: block stages 16 KB W (2 int4/thread, contiguous 512B rows) -> cvt bf16
// -> LDS; every wave reads the same A-frags (x8 reuse), 1 B-load + 2 ds_read_b128 +
// 2 MFMA per k-step. ONE barrier/phase; W prefetch depth 2, B depth 1, per-block K rot.
__global__ __launch_bounds__(512, 4) void qlinear_main(
    const int* __restrict__ W, const uint4* __restrict__ xf,
    const float* __restrict__ xsum, const float* __restrict__ scale_p,
    const float* __restrict__ zp_p, const float* __restrict__ bias,
    float* __restrict__ out) {
  __shared__ short smem[2 * SBUF];  // 20480 B

  const int tid = (int)threadIdx.x;
  const int w = tid >> 6;   // wave = token tile 0..7
  const int l = tid & 63;
  const int q = l >> 4;     // 0..3
  const int r = l & 15;     // A: row-in-tile; D: token-in-tile
  const int R0 = (int)blockIdx.x * 32;

  // --- staging geometry: thread t loads 2 int4 (j=0 -> rows 0..15, j=1 -> rows 16..31)
  const int row0 = tid >> 5;            // 0..15
  const int c0 = (tid & 31) * 4;        // int index in 128-int phase row span
  const int sl = c0 >> 5;               // k-step within phase
  const int kk = c0 & 31;
  const int g0 = (R0 + row0) * IN_F + c0;        // + pp*128
  const int g1 = (R0 + row0 + 16) * IN_F + c0;
  const int w0 = sl * SSL + row0 * SROW + kk;          // LDS short offset, j=0
  const int w1 = sl * SSL + (row0 + 16) * SROW + kk;   // j=1

  // --- fragment read offsets (shorts): lane(q,r), + s*SSL
  const int a0off = r * SROW + q * 8;
  const int a1off = (16 + r) * SROW + q * 8;

  const uint4* xp = xf + w * 64 + l;

  f32x4 acc0 = (f32x4)0.0f, acc1 = (f32x4)0.0f;

  const int p0 = ((int)blockIdx.x * 13) & 31;  // phase rotation (DRAM channel spread)

  int4 WnA, WnB;  // W(phase i+1)
  int4 WfA, WfB;  // W(phase i+2)
  uint4 Bc[4], Bn[4];

  // ---- preamble: stage phase p0 -> buf0; prefetch B(p0), W(p0+1) ----
  {
    const int ppk = p0 * 128;
    int4 t0 = *(const int4*)(W + g0 + ppk);
    int4 t1 = *(const int4*)(W + g1 + ppk);
#pragma unroll
    for (int s = 0; s < 4; ++s) Bc[s] = xp[(p0 * 4 + s) * 512];
    const int pp1k = (((p0 + 1) & 31) * 128);
    WnA = *(const int4*)(W + g0 + pp1k);
    WnB = *(const int4*)(W + g1 + pp1k);
    stash4(smem, w0, t0);
    stash4(smem, w1, t1);
  }
  phase_barrier();

#pragma unroll 1
  for (int it = 0; it < 16; ++it) {
    // ================= phase A = 2*it : compute buf0, stage W(2it+1) -> buf1 ======
    {
      const int ppf = ((2 * it + 2 + p0) & 31) * 128;   // W prefetch (depth 2)
      WfA = *(const int4*)(W + g0 + ppf);
      WfB = *(const int4*)(W + g1 + ppf);
      const int ppb = (2 * it + 1 + p0) & 31;           // B prefetch (depth 1)
#pragma unroll
      for (int s = 0; s < 4; ++s) Bn[s] = xp[(ppb * 4 + s) * 512];
#pragma unroll
      for (int s = 0; s < 4; ++s) {
        bf16x8 a0 = *(const bf16x8*)(smem + s * SSL + a0off);
        bf16x8 a1 = *(const bf16x8*)(smem + s * SSL + a1off);
        bf16x8 b = *(const bf16x8*)&Bc[s];
        acc0 = __builtin_amdgcn_mfma_f32_16x16x32_bf16(a0, b, acc0, 0, 0, 0);
        acc1 = __builtin_amdgcn_mfma_f32_16x16x32_bf16(a1, b, acc1, 0, 0, 0);
      }
      // stash into buf1: safe without a pre-barrier -- buf1's last readers (phase
      // 2it-1) retired their ds_reads before the previous phase_barrier().
      stash4(smem + SBUF, w0, WnA);
      stash4(smem + SBUF, w1, WnB);
      phase_barrier();
    }
    // ================= phase B = 2*it+1 : compute buf1, stage W(2it+2) -> buf0 ====
    {
      const int ppf = ((2 * it + 3 + p0) & 31) * 128;   // redundant wrap at tail: harmless
      WnA = *(const int4*)(W + g0 + ppf);
      WnB = *(const int4*)(W + g1 + ppf);
      const int ppb = (2 * it + 2 + p0) & 31;
#pragma unroll
      for (int s = 0; s < 4; ++s) Bc[s] = xp[(ppb * 4 + s) * 512];
#pragma unroll
      for (int s = 0; s < 4; ++s) {
        bf16x8 a0 = *(const bf16x8*)(smem + SBUF + s * SSL + a0off);
        bf16x8 a1 = *(const bf16x8*)(smem + SBUF + s * SSL + a1off);
        bf16x8 b = *(const bf16x8*)&Bn[s];
        acc0 = __builtin_amdgcn_mfma_f32_16x16x32_bf16(a0, b, acc0, 0, 0, 0);
        acc1 = __builtin_amdgcn_mfma_f32_16x16x32_bf16(a1, b, acc1, 0, 0, 0);
      }
      stash4(smem, w0, WfA);  // last iter: redundant re-stage of phase p0 -> harmless
      stash4(smem, w1, WfB);
      phase_barrier();
    }
  }

  // ---- epilogue: no reduction (full K per wave). D: col=lane&15 -> token, row=q*4+e.
  const float scale = *scale_p;
  const float zp = *zp_p;
  const int token = w * 16 + r;
  const float corr = -scale * zp * xsum[token];
  float* orow = out + token * OUT_F + R0 + q * 4;
  {
    const float4 bv = *(const float4*)(bias + R0 + q * 4);
    float4 o;
    o.x = acc0[0] * scale + corr + bv.x;
    o.y = acc0[1] * scale + corr + bv.y;
    o.z = acc0[2] * scale + corr + bv.z;
    o.w = acc0[3] * scale + corr + bv.w;
    *(float4*)(orow) = o;
  }
  {
    const float4 bv = *(const float4*)(bias + R0 + 16 + q * 4);
    float4 o;
    o.x = acc1[0] * scale + corr + bv.x;
    o.y = acc1[1] * scale + corr + bv.y;
    o.z = acc1[2] * scale + corr + bv.z;
    o.w = acc1[3] * scale + corr + bv.w;
    *(float4*)(orow + 16) = o;
  }
}

extern "C" void kernel_launch(void* const* d_in, const int* in_sizes, int n_in,
                              void* d_out, int out_size, void* d_ws, size_t ws_size,
                              hipStream_t stream) {
  const float* x = (const float*)d_in[0];        // [8,16,4096] f32
  const int* W = (const int*)d_in[1];            // [16384,4096] int32
  const float* scale = (const float*)d_in[2];    // scalar
  const float* zp = (const float*)d_in[3];       // scalar
  const float* bias = (const float*)d_in[4];     // [16384] f32
  float* out = (float*)d_out;                    // [8,16,16384] f32

  uint4* xf = (uint4*)d_ws;                              // 1 MiB bf16 frag image
  float* xsum = (float*)((char*)d_ws + (1 << 20));       // 128 floats

  prep_x<<<NTOK, 512, 0, stream>>>(x, xf, xsum);
  // Block covers 32 output rows -> grid = OUT_F/32 = 512 blocks of 512 threads.
  qlinear_main<<<OUT_F / 32, 512, 0, stream>>>(W, xf, xsum, scale, zp, bias, out);
}